// Round 3
// baseline (1380.006 us; speedup 1.0000x reference)
//
#include <hip/hip_runtime.h>
#include <hip/hip_bf16.h>
#include <math.h>

typedef unsigned short u16;
typedef __attribute__((ext_vector_type(8))) short short8;   // 8 bf16 (4 VGPRs)
typedef __attribute__((ext_vector_type(4))) float f32x4;    // MFMA C/D frag

// Problem constants: B=8, N=2048, D=DC=1024, K_centers=4, M = B*N = 16384.

__device__ __forceinline__ float bf2f(u16 b) {
  return __uint_as_float(((unsigned int)b) << 16);
}
__device__ __forceinline__ u16 f2bf(float f) {
  unsigned int u = __float_as_uint(f);
  u += 0x7FFFu + ((u >> 16) & 1u);   // round-to-nearest-even (finite inputs)
  return (u16)(u >> 16);
}
__device__ __forceinline__ float gelu_exact(float x) {
  return 0.5f * x * (1.0f + erff(x * 0.70710678118654752f));
}

// async 16B/lane global->LDS. LDS dest is wave-uniform base + lane*16.
__device__ __forceinline__ void cp16(const void* g, void* l) {
  __builtin_amdgcn_global_load_lds(
      (const __attribute__((address_space(1))) unsigned int*)g,
      (__attribute__((address_space(3))) unsigned int*)l, 16, 0, 0);
}

// ---------------------------------------------------------------------------
// GEMM: C[M,Nout] = A[M,K](bf16) @ Wt[Nout,K]^T(bf16)  (Wt row-major [Nout,K])
// 128x128 tile, BK=64, 4 waves (2x2), each wave 64x64 via 4x4 of 16x16x32 MFMA.
//
// R3 restructure: B operand bypasses LDS entirely — each lane's B-fragment
// (B[n=lane&15][k=(lane>>4)*8+j]) is one contiguous global_load_dwordx4 from
// the [Nout,K] weight matrix (L2-resident slab). B frags for iter k+1 are
// prefetched into registers while computing iter k. A stays in LDS
// (double-buffered 2x16KB) with a single barrier per iteration: the vmcnt(0)
// drain at the barrier covers cp16/B-loads issued one full compute phase
// earlier, so the m97-style barrier stall collapses. LDS traffic per
// block-iter: 96KB -> 48KB (ceiling ~1.1 -> ~2.2 PF).
//
// LDS quad-XOR swizzle keeps fragment ds_read_b128 <=2-way bank aliased.
// XCD swizzle: linear%8 -> XCD; within an XCD bx fastest => compact m-range
// per XCD, A fetched ~once from HBM (R2: FETCH 935->200MB).
// GATHER=true implements the jnp.roll fusion for fr1.
// MODE: 0 = gelu->bf16 out0 (ldo0)
//       1 = bias only -> out1 f32 (x_ring, ld 1024) + out0 bf16 (fus2, ldo0)
//       2 = bias only -> out0 bf16
//       4 = final: out0 f32 = gate*(c+bias) + (1-gate)*xring
//       5 = merged gate|fc1 (Nout=2048): n<1024 -> sigmoid f32 to out0[.,n];
//           n>=1024 -> gelu bf16 to out1[., n-1024]; bias2 for upper half
// ---------------------------------------------------------------------------
template <int MODE, bool GATHER>
__global__ __launch_bounds__(256) void gemm128(
    const u16* __restrict__ A, int lda, const u16* __restrict__ Wt, int K,
    const float* __restrict__ bias, const float* __restrict__ bias2,
    void* __restrict__ out0, int ldo0, void* __restrict__ out1,
    const float* __restrict__ gate, const float* __restrict__ xring) {
  __shared__ __align__(16) u16 As0[128 * 64];
  __shared__ __align__(16) u16 As1[128 * 64];

  const int tid = threadIdx.x;
  const int lane = tid & 63;
  const int wave = tid >> 6;     // 0..3
  const int wm = wave >> 1;      // wave row in 2x2
  const int wn = wave & 1;       // wave col

  // ---- XCD-aware block swizzle (gridDim.y divisible by 8) ----
  const unsigned linear = blockIdx.y * gridDim.x + blockIdx.x;
  const unsigned xcd = linear & 7u;
  const unsigned pos = linear >> 3;
  const unsigned bx = pos % gridDim.x;
  const unsigned by = xcd * (gridDim.y >> 3) + pos / gridDim.x;
  const int m0 = by * 128;
  const int n0 = bx * 128;

  const int srow = lane >> 3;    // 0..7: row within an 8-row staging chunk
  const int sq = lane & 7;       // quad (16B) within a 128B row
  const int sqs = sq ^ srow;     // swizzled global quad

  const int r16 = lane & 15;
  const int q4 = lane >> 4;      // 0..3

  // B-fragment base pointers (one row per ni, contiguous 16B at k + kk*32)
  const u16* bbase[4];
#pragma unroll
  for (int ni = 0; ni < 4; ni++)
    bbase[ni] = Wt + (long)(n0 + wn * 64 + ni * 16 + r16) * K + q4 * 8;

  f32x4 acc[4][4];
#pragma unroll
  for (int i = 0; i < 4; i++)
#pragma unroll
    for (int j = 0; j < 4; j++) acc[i][j] = (f32x4){0.f, 0.f, 0.f, 0.f};

  // ---- A-tile staging (cp16, swizzled) into buf for K-offset k0 ----
  auto stageA = [&](int k0, u16* buf) {
#pragma unroll
    for (int i = 0; i < 4; i++) {
      const int rloc = wave * 32 + i * 8 + srow;   // 0..127
      long gofs;
      if (GATHER) {
        const int seg = k0 >> 10;                  // uniform per iteration
        int shift;
        switch (seg) {
          case 0: shift = 1; break;
          case 1: shift = -1; break;
          case 2: shift = 0; break;
          case 3: shift = 2; break;
          case 4: shift = -2; break;
          case 5: shift = 4; break;
          default: shift = -4; break;
        }
        const int m = m0 + rloc;
        const int b = m >> 11;                     // N = 2048 = 2^11
        const int nsrc = ((m & 2047) - shift) & 2047;
        gofs = (long)((b << 11) | nsrc) * 1024 + (k0 & 1023) + sqs * 8;
      } else {
        gofs = (long)(m0 + rloc) * lda + k0 + sqs * 8;
      }
      cp16(A + gofs, &buf[(wave * 32 + i * 8) * 64]);
    }
  };
  auto loadB = [&](int k0, short8* bf) {
#pragma unroll
    for (int ni = 0; ni < 4; ni++)
#pragma unroll
      for (int kk = 0; kk < 2; kk++)
        bf[ni * 2 + kk] = *(const short8*)(bbase[ni] + k0 + kk * 32);
  };

  const int niter = K >> 6;
  short8 bcur[8], bnxt[8];
  stageA(0, As0);
  loadB(0, bcur);
  __syncthreads();

  u16* rd = As0;
  u16* wr = As1;
#pragma unroll 2
  for (int it = 0; it < niter; ++it) {
    if (it + 1 < niter) {
      loadB((it + 1) << 6, bnxt);     // register prefetch (in flight across barrier)
      stageA((it + 1) << 6, wr);      // LDS prefetch into other buffer
    }
    // compute on rd + bcur
#pragma unroll
    for (int kk = 0; kk < 2; kk++) {
      short8 af[4];
      const int q = (kk * 4 + q4) ^ (r16 & 7);
#pragma unroll
      for (int mi = 0; mi < 4; mi++) {
        const int row = wm * 64 + mi * 16 + r16;
        af[mi] = *(const short8*)&rd[row * 64 + q * 8];
      }
#pragma unroll
      for (int mi = 0; mi < 4; mi++)
#pragma unroll
        for (int ni = 0; ni < 4; ni++)
          acc[mi][ni] = __builtin_amdgcn_mfma_f32_16x16x32_bf16(
              af[mi], bcur[ni * 2 + kk], acc[mi][ni], 0, 0, 0);
    }
    __syncthreads();   // publishes wr (A it+1); drain covers old prefetches
    u16* t = rd; rd = wr; wr = t;
#pragma unroll
    for (int j = 0; j < 8; j++) bcur[j] = bnxt[j];
  }

  // epilogue: C/D layout col = lane&15, row = (lane>>4)*4 + reg
  const int ccol = r16;
  const int crow = q4 * 4;
#pragma unroll
  for (int mi = 0; mi < 4; mi++) {
#pragma unroll
    for (int ni = 0; ni < 4; ni++) {
#pragma unroll
      for (int r = 0; r < 4; r++) {
        const int m = m0 + wm * 64 + mi * 16 + crow + r;
        const int n = n0 + wn * 64 + ni * 16 + ccol;
        if (MODE == 5) {
          if (n < 1024) {
            const float v = acc[mi][ni][r] + bias[n];
            ((float*)out0)[(long)m * 1024 + n] = 1.0f / (1.0f + expf(-v));
          } else {
            const float v = acc[mi][ni][r] + bias2[n - 1024];
            ((u16*)out1)[(long)m * 1024 + (n - 1024)] = f2bf(gelu_exact(v));
          }
        } else {
          const float v = acc[mi][ni][r] + bias[n];
          if (MODE == 0) {
            ((u16*)out0)[(long)m * ldo0 + n] = f2bf(gelu_exact(v));
          } else if (MODE == 1) {
            ((float*)out1)[(long)m * 1024 + n] = v;
            ((u16*)out0)[(long)m * ldo0 + n] = f2bf(v);
          } else if (MODE == 2) {
            ((u16*)out0)[(long)m * ldo0 + n] = f2bf(v);
          } else {  // MODE 4
            const float g = gate[(long)m * 1024 + n];
            const float xr = xring[(long)m * 1024 + n];
            ((float*)out0)[(long)m * ldo0 + n] = g * v + (1.0f - g) * xr;
          }
        }
      }
    }
  }
}

// fp32 -> bf16 cast, 4 elems/thread
__global__ __launch_bounds__(256) void cast_bf16(const float* __restrict__ in,
                                                 u16* __restrict__ out, int n4) {
  const long i = (long)blockIdx.x * 256 + threadIdx.x;
  if (i < n4) {
    const float4 v = ((const float4*)in)[i];
    ushort4 o;
    o.x = f2bf(v.x); o.y = f2bf(v.y); o.z = f2bf(v.z); o.w = f2bf(v.w);
    ((ushort4*)out)[i] = o;
  }
}

// W[K,N] fp32 -> Wt[N,K] bf16, 32x32 LDS tile transpose. K = OUT row length.
__global__ __launch_bounds__(256) void transp_bf16(const float* __restrict__ in,
                                                   u16* __restrict__ out, int K,
                                                   int N) {
  __shared__ float tile[32][33];
  const int tx = threadIdx.x & 31;
  const int ty = threadIdx.x >> 5;  // 0..7
  const long r0 = (long)blockIdx.y * 32;
  const long c0 = (long)blockIdx.x * 32;
#pragma unroll
  for (int r = 0; r < 4; r++)
    tile[ty + r * 8][tx] = in[(r0 + ty + r * 8) * N + c0 + tx];
  __syncthreads();
#pragma unroll
  for (int r = 0; r < 4; r++)
    out[(c0 + ty + r * 8) * K + r0 + tx] = f2bf(tile[tx][ty + r * 8]);
}

// S[k,d] = sum_e tc_w2[d,e] * centers[k,e]   (tc2 folded into the logits)
// bc[k]  = sum_e tc_b2[e]   * centers[k,e]
__global__ __launch_bounds__(256) void fold_S(const float* __restrict__ tc_w2,
                                              const float* __restrict__ tc_b2,
                                              const float* __restrict__ centers,
                                              float* __restrict__ S,
                                              float* __restrict__ bc) {
  const int wave = threadIdx.x >> 6, lane = threadIdx.x & 63;
  if (blockIdx.x < 256) {
    const int d = blockIdx.x * 4 + wave;
    const float* row = tc_w2 + (long)d * 1024;
    float s0 = 0.f, s1 = 0.f, s2 = 0.f, s3 = 0.f;
    for (int e = lane; e < 1024; e += 64) {
      const float w = row[e];
      s0 += w * centers[e];
      s1 += w * centers[1024 + e];
      s2 += w * centers[2048 + e];
      s3 += w * centers[3072 + e];
    }
#pragma unroll
    for (int off = 32; off > 0; off >>= 1) {
      s0 += __shfl_xor(s0, off);
      s1 += __shfl_xor(s1, off);
      s2 += __shfl_xor(s2, off);
      s3 += __shfl_xor(s3, off);
    }
    if (lane == 0) {
      S[d] = s0; S[1024 + d] = s1; S[2048 + d] = s2; S[3072 + d] = s3;
    }
  } else {
    const int k = wave;
    float s = 0.f;
    for (int e = lane; e < 1024; e += 64) s += tc_b2[e] * centers[k * 1024 + e];
#pragma unroll
    for (int off = 32; off > 0; off >>= 1) s += __shfl_xor(s, off);
    if (lane == 0) bc[k] = s;
  }
}

// K=4 cluster from h2 directly: logits = h2 . S_k + bc_k, softmax,
// weighted = w @ centers.  One wave per token; bf16 into fus2[:, 1024:2048].
__global__ __launch_bounds__(256) void centers_kernel(
    const u16* __restrict__ h2, const float* __restrict__ S,
    const float* __restrict__ bc, const float* __restrict__ centers,
    u16* __restrict__ fus2) {
  const int lane = threadIdx.x & 63;
  const int wave = threadIdx.x >> 6;
  const long t = (long)blockIdx.x * 4 + wave;
  const u16* row = h2 + t * 1024;
  float d0 = 0.f, d1 = 0.f, d2 = 0.f, d3 = 0.f;
#pragma unroll
  for (int j = 0; j < 2; j++) {
    const int dbase = j * 512 + lane * 8;
    const short8 v = *(const short8*)(row + dbase);
#pragma unroll
    for (int e = 0; e < 8; e++) {
      const float x = bf2f((u16)v[e]);
      const int d = dbase + e;
      d0 += x * S[d];
      d1 += x * S[1024 + d];
      d2 += x * S[2048 + d];
      d3 += x * S[3072 + d];
    }
  }
#pragma unroll
  for (int off = 32; off > 0; off >>= 1) {
    d0 += __shfl_xor(d0, off);
    d1 += __shfl_xor(d1, off);
    d2 += __shfl_xor(d2, off);
    d3 += __shfl_xor(d3, off);
  }
  d0 += bc[0]; d1 += bc[1]; d2 += bc[2]; d3 += bc[3];
  const float mx = fmaxf(fmaxf(d0, d1), fmaxf(d2, d3));
  float e0 = expf(d0 - mx), e1 = expf(d1 - mx), e2 = expf(d2 - mx),
        e3 = expf(d3 - mx);
  const float inv = 1.0f / (e0 + e1 + e2 + e3);
  e0 *= inv; e1 *= inv; e2 *= inv; e3 *= inv;
#pragma unroll
  for (int j = 0; j < 2; j++) {
    const int dbase = j * 512 + lane * 8;
    short8 o;
#pragma unroll
    for (int e = 0; e < 8; e++) {
      const int d = dbase + e;
      const float wv = e0 * centers[d] + e1 * centers[1024 + d] +
                       e2 * centers[2048 + d] + e3 * centers[3072 + d];
      o[e] = (short)f2bf(wv);
    }
    *(short8*)(fus2 + t * 2048 + 1024 + dbase) = o;
  }
}

extern "C" void kernel_launch(void* const* d_in, const int* in_sizes, int n_in,
                              void* d_out, int out_size, void* d_ws,
                              size_t ws_size, hipStream_t stream) {
  const float* queries = (const float*)d_in[0];
  const float* fr_w1 = (const float*)d_in[1];
  const float* fr_b1 = (const float*)d_in[2];
  const float* fr_w2 = (const float*)d_in[3];
  const float* fr_b2 = (const float*)d_in[4];
  const float* tc_w1 = (const float*)d_in[5];
  const float* tc_b1 = (const float*)d_in[6];
  const float* tc_w2 = (const float*)d_in[7];
  const float* tc_b2 = (const float*)d_in[8];
  const float* centers = (const float*)d_in[9];
  const float* fc_w1 = (const float*)d_in[10];
  const float* fc_b1 = (const float*)d_in[11];
  const float* fc_w2 = (const float*)d_in[12];
  const float* fc_b2 = (const float*)d_in[13];
  const float* g_w = (const float*)d_in[14];
  const float* g_b = (const float*)d_in[15];

  char* ws = (char*)d_ws;
  u16* Wt1 = (u16*)ws; ws += (size_t)7168 * 1024 * 2;   // fr_w1^T
  u16* Wt2 = (u16*)ws; ws += (size_t)1024 * 1024 * 2;   // fr_w2^T
  u16* Wt3 = (u16*)ws; ws += (size_t)1024 * 1024 * 2;   // tc_w1^T
  u16* Wt6 = (u16*)ws; ws += (size_t)1024 * 1024 * 2;   // fc_w2^T
  u16* WtG = (u16*)ws; ws += (size_t)2048 * 2048 * 2;   // [g_w^T ; fc_w1^T]
  u16* Xb = (u16*)ws;  ws += (size_t)16384 * 1024 * 2;  // bf16 queries; reused h2, fch
  u16* h1 = (u16*)ws;  ws += (size_t)16384 * 1024 * 2;  // ring hidden
  float* xring = (float*)ws; ws += (size_t)16384 * 1024 * 4;  // x_ring fp32
  u16* fus2 = (u16*)ws; ws += (size_t)16384 * 2048 * 2; // [x_ring_bf16 | weighted]
  float* S = (float*)ws; ws += (size_t)4 * 1024 * 4;    // folded tc_w2@centers^T
  float* bc = (float*)ws; ws += 4 * 4;
  float* gate = (float*)d_out;  // gate f32 lives in d_out (read-then-overwrite)
  float* out = (float*)d_out;

  // --- precision conversions / folds (inputs restored by harness each call) ---
  cast_bf16<<<16384, 256, 0, stream>>>(queries, Xb, 16384 * 1024 / 4);
  transp_bf16<<<dim3(32, 224), 256, 0, stream>>>(fr_w1, Wt1, 7168, 1024);
  transp_bf16<<<dim3(32, 32), 256, 0, stream>>>(fr_w2, Wt2, 1024, 1024);
  transp_bf16<<<dim3(32, 32), 256, 0, stream>>>(tc_w1, Wt3, 1024, 1024);
  transp_bf16<<<dim3(32, 32), 256, 0, stream>>>(fc_w2, Wt6, 1024, 1024);
  transp_bf16<<<dim3(32, 64), 256, 0, stream>>>(g_w, WtG, 2048, 1024);
  transp_bf16<<<dim3(32, 64), 256, 0, stream>>>(fc_w1, WtG + (size_t)1024 * 2048,
                                                2048, 1024);
  fold_S<<<260, 256, 0, stream>>>(tc_w2, tc_b2, centers, S, bc);

  const dim3 grid(8, 128);  // Nout/128 x M/128
  // fr1: gelu(fusion @ fr_w1 + b1) with fused roll-gather -> h1
  gemm128<0, true><<<grid, 256, 0, stream>>>(Xb, 0, Wt1, 7168, fr_b1, nullptr,
                                             h1, 1024, nullptr, nullptr, nullptr);
  // fr2: x_ring = h1 @ fr_w2 + b2 -> xring(f32) + fus2[:, :1024](bf16)
  gemm128<1, false><<<grid, 256, 0, stream>>>(h1, 1024, Wt2, 1024, fr_b2,
                                              nullptr, fus2, 2048, xring,
                                              nullptr, nullptr);
  // tc1: h2 = gelu(x_ring @ tc_w1 + b1) -> Xb
  gemm128<0, false><<<grid, 256, 0, stream>>>(fus2, 2048, Wt3, 1024, tc_b1,
                                              nullptr, Xb, 1024, nullptr,
                                              nullptr, nullptr);
  // folded tc2 + softmax over 4 centers + weighted sum -> fus2[:, 1024:2048]
  centers_kernel<<<4096, 256, 0, stream>>>(Xb, S, bc, centers, fus2);
  // merged: gate = sigmoid(fus2@g_w+g_b) -> d_out ; fch = gelu(fus2@fc_w1+b1) -> Xb
  gemm128<5, false><<<dim3(16, 128), 256, 0, stream>>>(
      fus2, 2048, WtG, 2048, g_b, fc_b1, gate, 1024, Xb, nullptr, nullptr);
  // fc2 + final mix: out = gate*(fch @ fc_w2 + b2) + (1-gate)*x_ring
  gemm128<4, false><<<grid, 256, 0, stream>>>(Xb, 1024, Wt6, 1024, fc_b2,
                                              nullptr, out, 1024, nullptr,
                                              gate, xring);
}

// Round 4
// 880.710 us; speedup vs baseline: 1.5669x; 1.5669x over previous
//
#include <hip/hip_runtime.h>
#include <hip/hip_bf16.h>
#include <math.h>

typedef unsigned short u16;
typedef __attribute__((ext_vector_type(8))) short short8;   // 8 bf16 (4 VGPRs)
typedef __attribute__((ext_vector_type(4))) float f32x4;    // MFMA C/D frag

// Problem constants: B=8, N=2048, D=DC=1024, K_centers=4, M = B*N = 16384.
//
// R4 algebra (no fus2, no tc2, no tc1 as separate GEMMs):
//   h1    = gelu(ring_gather(x) @ fr_w1 + fr_b1)                 [240 GF]
//   joint1 over h1 (Nout=2048, K=1024):                          [68.7 GF]
//     x_ring = h1 @ fr_w2 + fr_b2          (f32 + bf16 copies)
//     h2     = gelu(h1 @ M2 + c2),  M2 = fr_w2@tc_w1 (precomputed GEMM),
//                                   c2 = fr_b2@tc_w1 + tc_b1
//   w = softmax(h2 @ S^T + bc),  S = centers@tc_w2^T (folded tc2) [small]
//   joint2 over x_ring_bf16 (Nout=2048, K=1024):                 [68.7 GF]
//     gate = sigmoid(x_ring@g_w_top  + w@G2 + g_b)   G2 = centers@g_w_bot
//     fch  = gelu  (x_ring@fc_w1_top + w@F2 + fc_b1) F2 = centers@fc_w1_bot
//   out = gate*(fch @ fc_w2 + fc_b2) + (1-gate)*x_ring           [34 GF]

__device__ __forceinline__ float bf2f(u16 b) {
  return __uint_as_float(((unsigned int)b) << 16);
}
__device__ __forceinline__ u16 f2bf(float f) {
  unsigned int u = __float_as_uint(f);
  u += 0x7FFFu + ((u >> 16) & 1u);   // round-to-nearest-even (finite inputs)
  return (u16)(u >> 16);
}
__device__ __forceinline__ float gelu_exact(float x) {
  return 0.5f * x * (1.0f + erff(x * 0.70710678118654752f));
}

// async 16B/lane global->LDS. LDS dest is wave-uniform base + lane*16.
__device__ __forceinline__ void cp16(const void* g, void* l) {
  __builtin_amdgcn_global_load_lds(
      (const __attribute__((address_space(1))) unsigned int*)g,
      (__attribute__((address_space(3))) unsigned int*)l, 16, 0, 0);
}

// ---------------------------------------------------------------------------
// GEMM: C[M,Nout] = A[M,K](bf16) @ Wt[Nout,K]^T(bf16)  (Wt row-major [Nout,K])
// 128x128 tile, BK=64, 4 waves (2x2), each wave 64x64 via 4x4 of 16x16x32 MFMA.
// R2-proven structure: both operands staged via cp16, two barriers per iter.
// (R3's B-register-bypass regressed 330->557us: scattered 64B B-loads + no
//  cooperative staging blew L2 and the barrier drain; reverted.)
// LDS quad-XOR swizzle keeps fragment ds_read_b128 <=2-way bank aliased.
// XCD swizzle: linear%8 -> XCD; within an XCD bx fastest => compact m-range
// per XCD, A fetched ~once from HBM (R2: FETCH 935->200MB).
// GATHER=true implements the jnp.roll fusion for fr1.
// MODE: 0 = gelu -> bf16 out0 (ldo0)
//       4 = final: out0 f32 = p0(gate)*(v+bias) + (1-p0)*p1(xring)
//       6 = no bias, bf16 out0 (M2T precompute)
//       7 = joint1: n<1024: v+bias -> out1 f32 & out0 bf16;
//           n>=1024: gelu(v+bias2) -> out2 bf16
//       8 = joint2: n<1024: sigmoid(v+bias[n]+w.G2T[n]) -> out0 f32;
//           n>=1024: gelu(v+bias2[n']+w.F2T[n']) -> out1 bf16
//           (p0 = w[M,4], p1 = G2T[1024,4], p2 = F2T[1024,4])
// ---------------------------------------------------------------------------
template <int MODE, bool GATHER>
__global__ __launch_bounds__(256) void gemm128(
    const u16* __restrict__ A, int lda, const u16* __restrict__ Wt, int K,
    const float* __restrict__ bias, const float* __restrict__ bias2,
    void* __restrict__ out0, int ldo0, void* __restrict__ out1,
    void* __restrict__ out2, const float* __restrict__ p0,
    const float* __restrict__ p1, const float* __restrict__ p2) {
  __shared__ __align__(16) u16 As[128 * 64];
  __shared__ __align__(16) u16 Bs[128 * 64];

  const int tid = threadIdx.x;
  const int lane = tid & 63;
  const int wave = tid >> 6;     // 0..3
  const int wm = wave >> 1;      // wave row in 2x2
  const int wn = wave & 1;       // wave col

  // ---- XCD-aware block swizzle (gridDim.y divisible by 8) ----
  const unsigned linear = blockIdx.y * gridDim.x + blockIdx.x;
  const unsigned xcd = linear & 7u;
  const unsigned pos = linear >> 3;
  const unsigned bx = pos % gridDim.x;
  const unsigned by = xcd * (gridDim.y >> 3) + pos / gridDim.x;
  const int m0 = by * 128;
  const int n0 = bx * 128;

  const int srow = lane >> 3;    // 0..7: row within an 8-row staging chunk
  const int sq = lane & 7;       // quad (16B) within a 128B row
  const int sqs = sq ^ srow;     // swizzled global quad

  f32x4 acc[4][4];
#pragma unroll
  for (int i = 0; i < 4; i++)
#pragma unroll
    for (int j = 0; j < 4; j++) acc[i][j] = (f32x4){0.f, 0.f, 0.f, 0.f};

  for (int k0 = 0; k0 < K; k0 += 64) {
    // ---- stage A tile (16 KB): As[row][q] <- A[m0+row][k0 + (q^(row&7))*8 ..]
#pragma unroll
    for (int i = 0; i < 4; i++) {
      const int rloc = wave * 32 + i * 8 + srow;   // 0..127
      long gofs;
      if (GATHER) {
        const int seg = k0 >> 10;                  // uniform per iteration
        int shift;
        switch (seg) {
          case 0: shift = 1; break;
          case 1: shift = -1; break;
          case 2: shift = 0; break;
          case 3: shift = 2; break;
          case 4: shift = -2; break;
          case 5: shift = 4; break;
          default: shift = -4; break;
        }
        const int m = m0 + rloc;
        const int b = m >> 11;                     // N = 2048 = 2^11
        const int nsrc = ((m & 2047) - shift) & 2047;
        gofs = (long)((b << 11) | nsrc) * 1024 + (k0 & 1023) + sqs * 8;
      } else {
        gofs = (long)(m0 + rloc) * lda + k0 + sqs * 8;
      }
      cp16(A + gofs, &As[(wave * 32 + i * 8) * 64]);
    }
    // ---- stage B tile: Bs[nrow][q] <- Wt[n0+nrow][k0 + (q^(nrow&7))*8 ..]
#pragma unroll
    for (int i = 0; i < 4; i++) {
      const int rloc = wave * 32 + i * 8 + srow;
      const long gofs = (long)(n0 + rloc) * K + k0 + sqs * 8;
      cp16(Wt + gofs, &Bs[(wave * 32 + i * 8) * 64]);
    }
    __syncthreads();

    const int q4 = lane >> 4;     // 0..3
    const int r16 = lane & 15;
#pragma unroll
    for (int kk = 0; kk < 2; kk++) {
      short8 af[4], bf[4];
#pragma unroll
      for (int mi = 0; mi < 4; mi++) {
        const int row = wm * 64 + mi * 16 + r16;
        const int q = (kk * 4 + q4) ^ (row & 7);
        af[mi] = *(const short8*)&As[row * 64 + q * 8];
      }
#pragma unroll
      for (int ni = 0; ni < 4; ni++) {
        const int row = wn * 64 + ni * 16 + r16;
        const int q = (kk * 4 + q4) ^ (row & 7);
        bf[ni] = *(const short8*)&Bs[row * 64 + q * 8];
      }
#pragma unroll
      for (int mi = 0; mi < 4; mi++)
#pragma unroll
        for (int ni = 0; ni < 4; ni++)
          acc[mi][ni] = __builtin_amdgcn_mfma_f32_16x16x32_bf16(
              af[mi], bf[ni], acc[mi][ni], 0, 0, 0);
    }
    __syncthreads();
  }

  // epilogue: C/D layout col = lane&15, row = (lane>>4)*4 + reg
  const int ccol = lane & 15;
  const int crow = (lane >> 4) * 4;
#pragma unroll
  for (int mi = 0; mi < 4; mi++) {
#pragma unroll
    for (int r = 0; r < 4; r++) {
      const int m = m0 + wm * 64 + mi * 16 + crow + r;
      float4 wrow;
      if (MODE == 8) wrow = *(const float4*)(p0 + (size_t)m * 4);
#pragma unroll
      for (int ni = 0; ni < 4; ni++) {
        const int n = n0 + wn * 64 + ni * 16 + ccol;
        const float v = acc[mi][ni][r];
        if (MODE == 0) {
          ((u16*)out0)[(long)m * ldo0 + n] = f2bf(gelu_exact(v + bias[n]));
        } else if (MODE == 4) {
          const float g = p0[(long)m * 1024 + n];
          const float xr = p1[(long)m * 1024 + n];
          ((float*)out0)[(long)m * ldo0 + n] =
              g * (v + bias[n]) + (1.0f - g) * xr;
        } else if (MODE == 6) {
          ((u16*)out0)[(long)m * ldo0 + n] = f2bf(v);
        } else if (MODE == 7) {
          if (n < 1024) {
            const float s = v + bias[n];
            ((float*)out1)[(long)m * 1024 + n] = s;
            ((u16*)out0)[(long)m * 1024 + n] = f2bf(s);
          } else {
            const int nn = n - 1024;
            ((u16*)out2)[(long)m * 1024 + nn] = f2bf(gelu_exact(v + bias2[nn]));
          }
        } else if (MODE == 8) {
          if (n < 1024) {
            const float4 g2 = *(const float4*)(p1 + (size_t)n * 4);
            const float s = v + bias[n] + wrow.x * g2.x + wrow.y * g2.y +
                            wrow.z * g2.z + wrow.w * g2.w;
            ((float*)out0)[(long)m * 1024 + n] = 1.0f / (1.0f + expf(-s));
          } else {
            const int nn = n - 1024;
            const float4 f2 = *(const float4*)(p2 + (size_t)nn * 4);
            const float s = v + bias2[nn] + wrow.x * f2.x + wrow.y * f2.y +
                            wrow.z * f2.z + wrow.w * f2.w;
            ((u16*)out1)[(long)m * 1024 + nn] = f2bf(gelu_exact(s));
          }
        }
      }
    }
  }
}

// fp32 -> bf16 cast, 4 elems/thread
__global__ __launch_bounds__(256) void cast_bf16(const float* __restrict__ in,
                                                 u16* __restrict__ out, int n4) {
  const long i = (long)blockIdx.x * 256 + threadIdx.x;
  if (i < n4) {
    const float4 v = ((const float4*)in)[i];
    ushort4 o;
    o.x = f2bf(v.x); o.y = f2bf(v.y); o.z = f2bf(v.z); o.w = f2bf(v.w);
    ((ushort4*)out)[i] = o;
  }
}

// W[K,N] fp32 -> Wt[N,K] bf16, 32x32 LDS tile transpose. K = OUT row length.
__global__ __launch_bounds__(256) void transp_bf16(const float* __restrict__ in,
                                                   u16* __restrict__ out, int K,
                                                   int N) {
  __shared__ float tile[32][33];
  const int tx = threadIdx.x & 31;
  const int ty = threadIdx.x >> 5;  // 0..7
  const long r0 = (long)blockIdx.y * 32;
  const long c0 = (long)blockIdx.x * 32;
#pragma unroll
  for (int r = 0; r < 4; r++)
    tile[ty + r * 8][tx] = in[(r0 + ty + r * 8) * N + c0 + tx];
  __syncthreads();
#pragma unroll
  for (int r = 0; r < 4; r++)
    out[(c0 + ty + r * 8) * K + r0 + tx] = f2bf(tile[tx][ty + r * 8]);
}

// All small precomputed folds in one launch (769 blocks, 4 waves each):
//  blocks [0,256):   n = b*4+wave: G2T[n][k] = sum_e centers[k][e]*GbT[n][e]
//                                  F2T[n][k] = sum_e centers[k][e]*FbT[n][e]
//  blocks [256,512): j: c2[j] = sum_e fr_b2[e]*Wt3[j][e] + tc_b1[j]
//  blocks [512,768): d: S[k*1024+d] = sum_e tc_w2[d][e]*centers[k][e]
//  block 768:        k = wave: bc[k] = sum_e tc_b2[e]*centers[k][e]
__global__ __launch_bounds__(256) void fold_all(
    const u16* __restrict__ GbT, const u16* __restrict__ FbT,
    const u16* __restrict__ Wt3, const float* __restrict__ centers,
    const float* __restrict__ fr_b2, const float* __restrict__ tc_b1,
    const float* __restrict__ tc_w2, const float* __restrict__ tc_b2,
    float* __restrict__ G2T, float* __restrict__ F2T, float* __restrict__ c2,
    float* __restrict__ S, float* __restrict__ bc) {
  const int b = blockIdx.x;
  const int wave = threadIdx.x >> 6, lane = threadIdx.x & 63;
  if (b < 256) {
    const int n = b * 4 + wave;
    float g[4] = {0.f, 0.f, 0.f, 0.f}, f[4] = {0.f, 0.f, 0.f, 0.f};
#pragma unroll
    for (int p = 0; p < 2; p++) {
      const int base = p * 512 + lane * 8;
      const short8 gv = *(const short8*)(GbT + (long)n * 1024 + base);
      const short8 fv = *(const short8*)(FbT + (long)n * 1024 + base);
#pragma unroll
      for (int e = 0; e < 8; e++) {
        const float ge = bf2f((u16)gv[e]), fe = bf2f((u16)fv[e]);
#pragma unroll
        for (int k = 0; k < 4; k++) {
          const float c = centers[k * 1024 + base + e];
          g[k] += ge * c;
          f[k] += fe * c;
        }
      }
    }
#pragma unroll
    for (int k = 0; k < 4; k++)
#pragma unroll
      for (int off = 32; off > 0; off >>= 1) {
        g[k] += __shfl_xor(g[k], off);
        f[k] += __shfl_xor(f[k], off);
      }
    if (lane == 0) {
#pragma unroll
      for (int k = 0; k < 4; k++) {
        G2T[n * 4 + k] = g[k];
        F2T[n * 4 + k] = f[k];
      }
    }
  } else if (b < 512) {
    const int j = (b - 256) * 4 + wave;
    float s = 0.f;
#pragma unroll
    for (int p = 0; p < 2; p++) {
      const int base = p * 512 + lane * 8;
      const short8 wv = *(const short8*)(Wt3 + (long)j * 1024 + base);
#pragma unroll
      for (int e = 0; e < 8; e++) s += fr_b2[base + e] * bf2f((u16)wv[e]);
    }
#pragma unroll
    for (int off = 32; off > 0; off >>= 1) s += __shfl_xor(s, off);
    if (lane == 0) c2[j] = s + tc_b1[j];
  } else if (b < 768) {
    const int d = (b - 512) * 4 + wave;
    const float* row = tc_w2 + (long)d * 1024;
    float s0 = 0.f, s1 = 0.f, s2 = 0.f, s3 = 0.f;
    for (int e = lane; e < 1024; e += 64) {
      const float w = row[e];
      s0 += w * centers[e];
      s1 += w * centers[1024 + e];
      s2 += w * centers[2048 + e];
      s3 += w * centers[3072 + e];
    }
#pragma unroll
    for (int off = 32; off > 0; off >>= 1) {
      s0 += __shfl_xor(s0, off);
      s1 += __shfl_xor(s1, off);
      s2 += __shfl_xor(s2, off);
      s3 += __shfl_xor(s3, off);
    }
    if (lane == 0) {
      S[d] = s0; S[1024 + d] = s1; S[2048 + d] = s2; S[3072 + d] = s3;
    }
  } else {
    const int k = wave;
    float s = 0.f;
    for (int e = lane; e < 1024; e += 64) s += tc_b2[e] * centers[k * 1024 + e];
#pragma unroll
    for (int off = 32; off > 0; off >>= 1) s += __shfl_xor(s, off);
    if (lane == 0) bc[k] = s;
  }
}

// w = softmax(h2 @ S^T + bc) over 4 centers; one wave per token -> w[t][0..3]
__global__ __launch_bounds__(256) void centers_kernel(
    const u16* __restrict__ h2, const float* __restrict__ S,
    const float* __restrict__ bc, float* __restrict__ wtok) {
  const int lane = threadIdx.x & 63;
  const int wave = threadIdx.x >> 6;
  const long t = (long)blockIdx.x * 4 + wave;
  const u16* row = h2 + t * 1024;
  float d0 = 0.f, d1 = 0.f, d2 = 0.f, d3 = 0.f;
#pragma unroll
  for (int j = 0; j < 2; j++) {
    const int dbase = j * 512 + lane * 8;
    const short8 v = *(const short8*)(row + dbase);
#pragma unroll
    for (int e = 0; e < 8; e++) {
      const float x = bf2f((u16)v[e]);
      const int d = dbase + e;
      d0 += x * S[d];
      d1 += x * S[1024 + d];
      d2 += x * S[2048 + d];
      d3 += x * S[3072 + d];
    }
  }
#pragma unroll
  for (int off = 32; off > 0; off >>= 1) {
    d0 += __shfl_xor(d0, off);
    d1 += __shfl_xor(d1, off);
    d2 += __shfl_xor(d2, off);
    d3 += __shfl_xor(d3, off);
  }
  if (lane == 0) {
    d0 += bc[0]; d1 += bc[1]; d2 += bc[2]; d3 += bc[3];
    const float mx = fmaxf(fmaxf(d0, d1), fmaxf(d2, d3));
    float e0 = expf(d0 - mx), e1 = expf(d1 - mx), e2 = expf(d2 - mx),
          e3 = expf(d3 - mx);
    const float inv = 1.0f / (e0 + e1 + e2 + e3);
    *(float4*)(wtok + t * 4) = (float4){e0 * inv, e1 * inv, e2 * inv, e3 * inv};
  }
}

extern "C" void kernel_launch(void* const* d_in, const int* in_sizes, int n_in,
                              void* d_out, int out_size, void* d_ws,
                              size_t ws_size, hipStream_t stream) {
  const float* queries = (const float*)d_in[0];
  const float* fr_w1 = (const float*)d_in[1];
  const float* fr_b1 = (const float*)d_in[2];
  const float* fr_w2 = (const float*)d_in[3];
  const float* fr_b2 = (const float*)d_in[4];
  const float* tc_w1 = (const float*)d_in[5];
  const float* tc_b1 = (const float*)d_in[6];
  const float* tc_w2 = (const float*)d_in[7];
  const float* tc_b2 = (const float*)d_in[8];
  const float* centers = (const float*)d_in[9];
  const float* fc_w1 = (const float*)d_in[10];
  const float* fc_b1 = (const float*)d_in[11];
  const float* fc_w2 = (const float*)d_in[12];
  const float* fc_b2 = (const float*)d_in[13];
  const float* g_w = (const float*)d_in[14];
  const float* g_b = (const float*)d_in[15];

  char* ws = (char*)d_ws;
  u16* Wt1 = (u16*)ws; ws += (size_t)7168 * 1024 * 2;   // fr_w1^T
  u16* Wt3 = (u16*)ws; ws += (size_t)1024 * 1024 * 2;   // tc_w1^T
  u16* Wt6 = (u16*)ws; ws += (size_t)1024 * 1024 * 2;   // fc_w2^T
  u16* WtJ = (u16*)ws; ws += (size_t)2048 * 1024 * 2;   // [fr_w2^T ; M2^T]
  u16* WtG2 = (u16*)ws; ws += (size_t)2048 * 1024 * 2;  // [g_w_top^T ; fc_w1_top^T]
  u16* Fw2b = (u16*)ws; ws += (size_t)1024 * 1024 * 2;  // fr_w2 bf16 (row-major)
  u16* GbT = (u16*)ws; ws += (size_t)1024 * 1024 * 2;   // g_w_bot^T bf16
  u16* FbT = (u16*)ws; ws += (size_t)1024 * 1024 * 2;   // fc_w1_bot^T bf16
  u16* Xb = (u16*)ws;  ws += (size_t)16384 * 1024 * 2;  // bf16 queries -> h2
  u16* h1 = (u16*)ws;  ws += (size_t)16384 * 1024 * 2;  // ring hidden -> fch
  u16* xrb = (u16*)ws; ws += (size_t)16384 * 1024 * 2;  // x_ring bf16
  float* xring = (float*)ws; ws += (size_t)16384 * 1024 * 4;  // x_ring f32
  float* wtok = (float*)ws; ws += (size_t)16384 * 4 * 4;      // softmax weights
  float* S = (float*)ws; ws += (size_t)4 * 1024 * 4;
  float* G2T = (float*)ws; ws += (size_t)1024 * 4 * 4;
  float* F2T = (float*)ws; ws += (size_t)1024 * 4 * 4;
  float* c2 = (float*)ws; ws += (size_t)1024 * 4;
  float* bc = (float*)ws; ws += 16;
  float* gate = (float*)d_out;  // gate f32 in d_out (read-then-overwrite)
  float* out = (float*)d_out;

  // --- conversions / transposes ---
  cast_bf16<<<16384, 256, 0, stream>>>(queries, Xb, 16384 * 1024 / 4);
  cast_bf16<<<1024, 256, 0, stream>>>(fr_w2, Fw2b, 1024 * 1024 / 4);
  transp_bf16<<<dim3(32, 224), 256, 0, stream>>>(fr_w1, Wt1, 7168, 1024);
  transp_bf16<<<dim3(32, 32), 256, 0, stream>>>(tc_w1, Wt3, 1024, 1024);
  transp_bf16<<<dim3(32, 32), 256, 0, stream>>>(fc_w2, Wt6, 1024, 1024);
  transp_bf16<<<dim3(32, 32), 256, 0, stream>>>(fr_w2, WtJ, 1024, 1024);
  transp_bf16<<<dim3(32, 32), 256, 0, stream>>>(g_w, WtG2, 1024, 1024);
  transp_bf16<<<dim3(32, 32), 256, 0, stream>>>(fc_w1,
                                                WtG2 + (size_t)1024 * 1024,
                                                1024, 1024);
  transp_bf16<<<dim3(32, 32), 256, 0, stream>>>(g_w + (size_t)1024 * 1024, GbT,
                                                1024, 1024);
  transp_bf16<<<dim3(32, 32), 256, 0, stream>>>(fc_w1 + (size_t)1024 * 1024,
                                                FbT, 1024, 1024);
  // --- small folds: G2T/F2T, c2, S, bc ---
  fold_all<<<769, 256, 0, stream>>>(GbT, FbT, Wt3, centers, fr_b2, tc_b1,
                                    tc_w2, tc_b2, G2T, F2T, c2, S, bc);
  // --- M2^T = (fr_w2 @ tc_w1)^T via GEMM: C[j][i] = sum_e Wt3[j][e]*Fw2b[i][e]
  gemm128<6, false><<<dim3(8, 8), 256, 0, stream>>>(
      Wt3, 1024, Fw2b, 1024, nullptr, nullptr, WtJ + (size_t)1024 * 1024, 1024,
      nullptr, nullptr, nullptr, nullptr, nullptr);

  // --- main chain ---
  // fr1: h1 = gelu(ring_gather(x) @ fr_w1 + fr_b1)
  gemm128<0, true><<<dim3(8, 128), 256, 0, stream>>>(
      Xb, 0, Wt1, 7168, fr_b1, nullptr, h1, 1024, nullptr, nullptr, nullptr,
      nullptr, nullptr);
  // joint1: x_ring (f32 + bf16) and h2 in one pass over h1
  gemm128<7, false><<<dim3(16, 128), 256, 0, stream>>>(
      h1, 1024, WtJ, 1024, fr_b2, c2, xrb, 1024, xring, Xb, nullptr, nullptr,
      nullptr);
  // w = softmax(h2 @ S^T + bc)
  centers_kernel<<<4096, 256, 0, stream>>>(Xb, S, bc, wtok);
  // joint2: gate -> d_out, fch -> h1 (w-corrections in epilogue)
  gemm128<8, false><<<dim3(16, 128), 256, 0, stream>>>(
      xrb, 1024, WtG2, 1024, g_b, fc_b1, gate, 1024, h1, nullptr, wtok, G2T,
      F2T);
  // fc2 + final mix: out = gate*(fch @ fc_w2 + fc_b2) + (1-gate)*x_ring
  gemm128<4, false><<<dim3(8, 128), 256, 0, stream>>>(
      h1, 1024, Wt6, 1024, fc_b2, nullptr, out, 1024, nullptr, nullptr, gate,
      xring, nullptr);
}